// Round 2
// baseline (550.893 us; speedup 1.0000x reference)
//
#include <hip/hip_runtime.h>
#include <hip/hip_bf16.h>
#include <cstdint>
#include <math.h>

#define NDIM 1024
#define BDIM 32
#define DDIM 64
#define NEDGE 5

struct Keys { uint32_t a[NEDGE]; uint32_t b[NEDGE]; };

// JAX Threefry-2x32, 20 rounds. Matches jax/_src/prng.py exactly.
#define TF_R(r) do { x0 += x1; x1 = (x1 << (r)) | (x1 >> (32 - (r))); x1 ^= x0; } while (0)
__host__ __device__ inline void tf2x32(uint32_t k0, uint32_t k1,
                                       uint32_t x0, uint32_t x1,
                                       uint32_t& o0, uint32_t& o1) {
  const uint32_t ks2 = k0 ^ k1 ^ 0x1BD11BDAu;
  x0 += k0; x1 += k1;
  TF_R(13); TF_R(15); TF_R(26); TF_R(6);
  x0 += k1; x1 += ks2 + 1u;
  TF_R(17); TF_R(29); TF_R(16); TF_R(24);
  x0 += ks2; x1 += k0 + 2u;
  TF_R(13); TF_R(15); TF_R(26); TF_R(6);
  x0 += k0; x1 += k1 + 3u;
  TF_R(17); TF_R(29); TF_R(16); TF_R(24);
  x0 += k1; x1 += ks2 + 4u;
  TF_R(13); TF_R(15); TF_R(26); TF_R(6);
  x0 += ks2; x1 += k0 + 5u;
  o0 = x0; o1 = x1;
}

// Partitionable threefry bits for linear position p (< 2^32):
// bits = o0 ^ o1 of tf(key; x0=0, x1=p).
__device__ __forceinline__ uint32_t tf_bits(uint32_t k0, uint32_t k1, uint32_t p) {
  uint32_t o0, o1;
  tf2x32(k0, k1, 0u, p, o0, o1);
  return o0 ^ o1;
}

// bits -> uniform(1e-10,1) -> gumbel, replicating JAX's exact f32 op sequence
// (separate mul/add rounding — no FMA contraction), double-precision logs.
__device__ __forceinline__ float gumbel_bits(uint32_t bits) {
  float f = __uint_as_float((bits >> 9) | 0x3F800000u) - 1.0f;
  // (maxval-minval) in f32 is exactly 1.0f; keep JAX's separate mul+add.
  float u = fmaxf(1e-10f, __fadd_rn(__fmul_rn(f, 1.0f - 1e-10f), 1e-10f));
  float t = -(float)log((double)u);
  return -(float)log((double)t);
}

// Phase A: logits[b][n] = W2 . tanh(W1^T [curr_b; nodes_bn] + b1) + b2
__global__ __launch_bounds__(256) void k_logits(
    const float* __restrict__ nodes, const int* __restrict__ nn,
    const float* __restrict__ W1, const float* __restrict__ b1,
    const float* __restrict__ W2, const float* __restrict__ b2,
    float* __restrict__ logits) {
  const int lane = threadIdx.x & 63;
  const int gw = (blockIdx.x * 256 + threadIdx.x) >> 6;   // wave id = (b,n)
  const int b = gw >> 10, n = gw & (NDIM - 1);
  const int cn = nn[b];
  const float a = nodes[((size_t)b * NDIM + cn) * DDIM + lane];  // curr
  const float x = nodes[((size_t)b * NDIM + n) * DDIM + lane];
  float acc = b1[lane];
#pragma unroll 8
  for (int k = 0; k < 64; ++k)
    acc = fmaf(__shfl(a, k), W1[k * DDIM + lane], acc);
#pragma unroll 8
  for (int k = 0; k < 64; ++k)
    acc = fmaf(__shfl(x, k), W1[(64 + k) * DDIM + lane], acc);
  float p = tanhf(acc) * W2[lane];
  for (int off = 32; off; off >>= 1) p += __shfl_down(p, off);
  if (lane == 0) logits[b * NDIM + n] = p + b2[0];
}

// Phase B: weights_out = weights_in, row nn[b] patched with logits for c<nn[b]
__global__ __launch_bounds__(256) void k_weights(
    const float* __restrict__ w_in, const float* __restrict__ logits,
    const int* __restrict__ nn, float* __restrict__ w_out) {
  const int i = blockIdx.x * 256 + threadIdx.x;  // float4 index
  const int c4 = i & 255;
  const int r = (i >> 8) & (NDIM - 1);
  const int b = i >> 18;
  float4 v = ((const float4*)w_in)[i];
  const int n = nn[b];
  if (r == n) {
    float* vf = (float*)&v;
    const int c0 = c4 * 4;
#pragma unroll
    for (int j = 0; j < 4; ++j)
      if (c0 + j < n) vf[j] = logits[b * NDIM + c0 + j];
  }
  ((float4*)w_out)[i] = v;
}

// Phase C: one block per (b, r). 5 gumbel argmaxes over c<=nn[b], OR into adj.
// Int fast path (argmax over bits>>9; gumbel monotone in bits) unless the
// row has nonzero weights (only the patched logit row) -> float fallback.
__global__ __launch_bounds__(256) void k_adj(
    const float* __restrict__ adj_in, const float* __restrict__ w_in,
    const float* __restrict__ logits, const int* __restrict__ nn_arr,
    float* __restrict__ adj_out, Keys keys) {
  const int b = blockIdx.x;    // 0..31
  const int r = blockIdx.y;    // 0..1023
  const int tid = threadIdx.x;
  const int nn = nn_arr[b];
  const bool active = (r <= nn);

  __shared__ unsigned long long red[NEDGE][4];
  __shared__ int hitc[NEDGE];
  __shared__ int flg;
  if (tid == 0) flg = 0;
  if (tid < NEDGE) hitc[tid] = 1024;   // no hit
  __syncthreads();

  const size_t row = ((size_t)b * NDIM + r) * NDIM;
  const uint32_t pbase = (uint32_t)b * (NDIM * NDIM) + (uint32_t)r * NDIM;

  if (active) {
    unsigned long long best[NEDGE];
#pragma unroll
    for (int e = 0; e < NEDGE; ++e) best[e] = 0ull;
    bool wnz = false;
    for (int c = tid; c <= nn; c += 256) {
      float w = w_in[row + c];
      if (r == nn && c < nn) w = logits[b * NDIM + c];
      wnz |= (w != 0.f);
      const uint32_t p = pbase + (uint32_t)c;
      const unsigned long long lo = (unsigned long long)(1024 - c); // tie -> smaller c
#pragma unroll
      for (int e = 0; e < NEDGE; ++e) {
        const uint32_t bits = tf_bits(keys.a[e], keys.b[e], p);
        const unsigned long long pk =
            ((unsigned long long)(bits >> 9) << 32) | lo;
        if (pk > best[e]) best[e] = pk;
      }
    }
    if (wnz) flg = 1;
#pragma unroll
    for (int e = 0; e < NEDGE; ++e) {
      unsigned long long v = best[e];
      for (int off = 32; off; off >>= 1) {
        unsigned long long o = __shfl_xor(v, off);
        if (o > v) v = o;
      }
      if ((tid & 63) == 0) red[e][tid >> 6] = v;
    }
  }
  __syncthreads();
  if (active && tid < NEDGE) {
    unsigned long long v = red[tid][0];
    for (int w = 1; w < 4; ++w) if (red[tid][w] > v) v = red[tid][w];
    hitc[tid] = 1024 - (int)(v & 0xFFFFFFFFull);
  }
  __syncthreads();

  if (flg) {  // block-uniform; only the patched logit row per batch
    unsigned long long fb[NEDGE];
#pragma unroll
    for (int e = 0; e < NEDGE; ++e) fb[e] = 0ull;
    for (int c = tid; c <= nn; c += 256) {
      float w = w_in[row + c];
      if (r == nn && c < nn) w = logits[b * NDIM + c];
      const uint32_t p = pbase + (uint32_t)c;
      const unsigned long long lo = (unsigned long long)(1024 - c);
#pragma unroll
      for (int e = 0; e < NEDGE; ++e) {
        const float pert = w + gumbel_bits(tf_bits(keys.a[e], keys.b[e], p));
        const uint32_t fu = __float_as_uint(pert);
        const uint32_t key = (fu & 0x80000000u) ? ~fu : (fu | 0x80000000u);
        const unsigned long long pk = ((unsigned long long)key << 32) | lo;
        if (pk > fb[e]) fb[e] = pk;
      }
    }
#pragma unroll
    for (int e = 0; e < NEDGE; ++e) {
      unsigned long long v = fb[e];
      for (int off = 32; off; off >>= 1) {
        unsigned long long o = __shfl_xor(v, off);
        if (o > v) v = o;
      }
      if ((tid & 63) == 0) red[e][tid >> 6] = v;
    }
    __syncthreads();
    if (tid < NEDGE) {
      unsigned long long v = red[tid][0];
      for (int w = 1; w < 4; ++w) if (red[tid][w] > v) v = red[tid][w];
      hitc[tid] = 1024 - (int)(v & 0xFFFFFFFFull);
    }
    __syncthreads();
  }

  // Write the row: OR-in hits, zero diagonal.
  float4 v = ((const float4*)(adj_in + row))[tid];
  float* vf = (float*)&v;
  const int c0 = tid * 4;
#pragma unroll
  for (int jx = 0; jx < 4; ++jx) {
    const int c = c0 + jx;
    float f = vf[jx];
#pragma unroll
    for (int e = 0; e < NEDGE; ++e)
      if (hitc[e] == c) f = 1.0f;
    if (c == r) f = 0.0f;
    vf[jx] = f;
  }
  ((float4*)(adj_out + row))[tid] = v;
}

extern "C" void kernel_launch(void* const* d_in, const int* in_sizes, int n_in,
                              void* d_out, int out_size, void* d_ws, size_t ws_size,
                              hipStream_t stream) {
  (void)in_sizes; (void)n_in; (void)out_size; (void)ws_size;
  const float* nodes = (const float*)d_in[0];
  const float* adj   = (const float*)d_in[1];
  const float* wts   = (const float*)d_in[2];
  const int*   nn    = (const int*)d_in[3];
  const float* W1    = (const float*)d_in[5];
  const float* b1    = (const float*)d_in[6];
  const float* W2    = (const float*)d_in[7];
  const float* b2    = (const float*)d_in[8];

  float* adj_out = (float*)d_out;
  float* w_out   = adj_out + (size_t)BDIM * NDIM * NDIM;
  float* logits  = (float*)d_ws;  // 32*1024 floats = 128 KB

  // folded keys: k_i = threefry2x32(key=(0,42), data=(0,i))  [jax.random.fold_in]
  Keys keys;
  for (int i = 0; i < NEDGE; ++i) {
    uint32_t o0, o1;
    tf2x32(0u, 42u, 0u, (uint32_t)i, o0, o1);
    keys.a[i] = o0; keys.b[i] = o1;
  }

  k_logits <<<dim3(BDIM * NDIM / 4), 256, 0, stream>>>(nodes, nn, W1, b1, W2, b2, logits);
  k_weights<<<dim3((size_t)BDIM * NDIM * NDIM / 4 / 256), 256, 0, stream>>>(wts, logits, nn, w_out);
  k_adj    <<<dim3(BDIM, NDIM), 256, 0, stream>>>(adj, wts, logits, nn, adj_out, keys);
}